// Round 4
// baseline (7105.183 us; speedup 1.0000x reference)
//
#include <hip/hip_runtime.h>

// Graph-attention sequential sweep as dataflow over the dependency DAG.
// Node i depends only on out-rows g[j] for j in neighbors[i], j<i, k<deg[i].
//
// R4 theory: R1/R2/R3 showed bit-identical ~660-680us across 2x occupancy,
// 4x MLP, and eager-softmax restructuring. The only invariant: 50000
// same-address atomicAdd grabs = one per ~13ns = exactly the same-line
// atomic service rate -> the counter IS the serializer.
// Fix: batched grabs (GRAB=16) -> 3125 atomics (16x cut). Deadlock-free
// unconditionally: each wave processes its batch IN ORDER, so the smallest
// unfinished id is always held by a resident wave whose batch-predecessors
// (all smaller ids) are finished and whose deps (< id) are finished.
//
// Also: eager online-softmax (R3) kept; gather extraction widened to 8 rows
// in flight (static-indexed, duplicate-clamped so no undefined values).
//
// Coherence scheme (NO buffer_inv / NO buffer_wbl2 anywhere):
//  - producer: out-row stores write-through to LLC (sc0 sc1); ej_new (the
//    combined payload+flag) via relaxed agent atomic, ordered after the row
//    stores by an explicit s_waitcnt(0).
//  - consumer: polls ej_new with relaxed agent loads (sc1, no L2 inv);
//    reads out-rows with NORMAL cached loads — safe because each 2KB row
//    occupies exclusive cachelines and is first read only after its ej_new
//    is seen nonzero, so no stale copy can exist in any cache.

constexpr int NN   = 50000;
constexpr int D    = 512;
constexpr int K    = 32;
constexpr int D4   = D / 4; // 128 float4 per row
constexpr int GRAB = 16;    // ids per counter grab

typedef float v4f __attribute__((ext_vector_type(4)));

__device__ __forceinline__ void store_f4_llc(float* p, float4 v) {
    // write-through to the memory-side Infinity Cache (device coherence point)
    v4f vv; vv.x = v.x; vv.y = v.y; vv.z = v.z; vv.w = v.w;
    asm volatile("global_store_dwordx4 %0, %1, off sc0 sc1"
                 :: "v"(p), "v"(vv) : "memory");
}

__global__ __launch_bounds__(256) void precomp_kernel(
    const float* __restrict__ feats,
    const float* __restrict__ wq_w, const float* __restrict__ wq_b,
    const float* __restrict__ wk_w, const float* __restrict__ wk_b,
    float* __restrict__ ei, float* __restrict__ ej_orig)
{
    int gw   = (int)((blockIdx.x * blockDim.x + threadIdx.x) >> 6); // global wave id
    int lane = threadIdx.x & 63;
    if (gw >= NN) return;
    const float4* row = (const float4*)feats + (size_t)gw * D4;
    const float4* q4  = (const float4*)wq_w;
    const float4* k4  = (const float4*)wk_w;
    float dq = 0.f, dk = 0.f;
#pragma unroll
    for (int c = 0; c < 2; ++c) {
        float4 v  = row[lane + 64 * c];
        float4 q  = q4[lane + 64 * c];
        float4 kk = k4[lane + 64 * c];
        dq += v.x * q.x + v.y * q.y + v.z * q.z + v.w * q.w;
        dk += v.x * kk.x + v.y * kk.y + v.z * kk.z + v.w * kk.w;
    }
#pragma unroll
    for (int off = 32; off > 0; off >>= 1) {
        dq += __shfl_down(dq, off, 64);
        dk += __shfl_down(dk, off, 64);
    }
    if (lane == 0) {
        ei[gw]      = dq + wq_b[0];
        ej_orig[gw] = dk + wk_b[0];
    }
}

__global__ __launch_bounds__(256) void attn_dataflow(
    const float* __restrict__ feats,
    const int* __restrict__ neighbors, const int* __restrict__ deg,
    const float* __restrict__ ei_arr, const float* __restrict__ ej_orig,
    const float* __restrict__ wk_w, const float* __restrict__ wk_b,
    int* ej_new, int* counter,
    float* out)
{
    const int lane = threadIdx.x & 63;
    const float4* f4  = (const float4*)feats;
    const float4* o4r = (const float4*)out;
    const float4* wk4 = (const float4*)wk_w;
    const float   wkb = wk_b[0];

    for (;;) {
        int base = 0;
        if (lane == 0) base = atomicAdd(counter, GRAB);
        base = __shfl(base, 0, 64);
        if (base >= NN) return;
        const int lim = (base + GRAB < NN) ? (base + GRAB) : NN;

        for (int id = base; id < lim; ++id) {
            const int d = deg[id];
            int nbr = 0;
            if (lane < K) nbr = neighbors[(size_t)id * K + lane];
            const bool valid = lane < d;             // d <= 32
            const bool isdep = valid && (nbr < id);

            const float4 c0 = f4[(size_t)id * D4 + lane];
            const float4 c1 = f4[(size_t)id * D4 + lane + 64];
            const float eii = ei_arr[id];

            float eij = 0.f;
            if (valid && !isdep) eij = eii * ej_orig[nbr];

            // ---- eager online-softmax over ready neighbors ----
            float4 acc0 = {0.f, 0.f, 0.f, 0.f};
            float4 acc1 = {0.f, 0.f, 0.f, 0.f};
            float m = -3.0e38f, s = 0.f;

            unsigned long long pend = __ballot(valid && !isdep);
            unsigned long long wait = __ballot(isdep);

            while (pend | wait) {
                if (!pend) {
                    int pv = 0;
                    const bool w = (wait >> lane) & 1ULL;
                    if (w) pv = __hip_atomic_load(&ej_new[nbr], __ATOMIC_RELAXED,
                                                  __HIP_MEMORY_SCOPE_AGENT);
                    unsigned long long ready = __ballot(w && pv != 0);
                    if (!ready) { __builtin_amdgcn_s_sleep(1); continue; }
                    if (w && pv != 0) eij = eii * __int_as_float(pv);
                    pend = ready;
                    wait &= ~ready;
                }
                // take up to 8 ready neighbors; static indexing throughout,
                // empty slots duplicate the last valid row (weight -> 0)
                int   js[8]; float ee[8];
                int   klast = 0;
#pragma unroll
                for (int t = 0; t < 8; ++t) {
                    const bool has = (pend != 0);            // wave-uniform
                    int k = has ? ((int)__ffsll(pend) - 1) : klast;
                    if (has) pend &= pend - 1;
                    klast = k;
                    float ev = __shfl(eij, k, 64);
                    ee[t] = has ? ev : -3.0e38f;             // invalid -> wt 0
                    js[t] = __shfl(nbr, k, 64);
                }
                float4 v0[8], v1[8];
#pragma unroll
                for (int t = 0; t < 8; ++t) {
                    const float4* sp = (js[t] < id) ? (o4r + (size_t)js[t] * D4)
                                                    : (f4  + (size_t)js[t] * D4);
                    v0[t] = sp[lane];
                    v1[t] = sp[lane + 64];
                }
                float mb = m;
#pragma unroll
                for (int t = 0; t < 8; ++t) mb = fmaxf(mb, ee[t]);
                if (mb > m) {
                    const float r = __expf(m - mb);
                    acc0.x *= r; acc0.y *= r; acc0.z *= r; acc0.w *= r;
                    acc1.x *= r; acc1.y *= r; acc1.z *= r; acc1.w *= r;
                    s *= r; m = mb;
                }
#pragma unroll
                for (int t = 0; t < 8; ++t) {
                    const float wt = __expf(ee[t] - m);      // invalid: exp(-inf)=0
                    s += wt;
                    acc0.x += wt * v0[t].x; acc0.y += wt * v0[t].y;
                    acc0.z += wt * v0[t].z; acc0.w += wt * v0[t].w;
                    acc1.x += wt * v1[t].x; acc1.y += wt * v1[t].y;
                    acc1.z += wt * v1[t].z; acc1.w += wt * v1[t].w;
                }
            }

            const float inv_s = (s > 0.f) ? (1.0f / s) : 0.f;  // d==0 -> acc==0
            float4 g0 = {c0.x + acc0.x * inv_s, c0.y + acc0.y * inv_s,
                         c0.z + acc0.z * inv_s, c0.w + acc0.w * inv_s};
            float4 g1 = {c1.x + acc1.x * inv_s, c1.y + acc1.y * inv_s,
                         c1.z + acc1.z * inv_s, c1.w + acc1.w * inv_s};
            float* orow = out + (size_t)id * D;
            store_f4_llc(orow + 4 * lane,        g0);
            store_f4_llc(orow + 4 * (lane + 64), g1);

            // ej_new[id] = g . wk + bk  (computed while row stores are in flight)
            float4 w0 = wk4[lane], w1 = wk4[lane + 64];
            float pd = g0.x * w0.x + g0.y * w0.y + g0.z * w0.z + g0.w * w0.w
                     + g1.x * w1.x + g1.y * w1.y + g1.z * w1.z + g1.w * w1.w;
#pragma unroll
            for (int off = 32; off > 0; off >>= 1)
                pd += __shfl_xor(pd, off, 64);

            int bits = __float_as_int(pd + wkb);
            if (bits == 0) bits = 1;   // avoid sentinel (+0.0 -> denormal)

            // order the row payload (at LLC) before the combined flag+payload
            __builtin_amdgcn_s_waitcnt(0);
            if (lane == 0)
                __hip_atomic_store(&ej_new[id], bits,
                                   __ATOMIC_RELAXED, __HIP_MEMORY_SCOPE_AGENT);
        }
    }
}

extern "C" void kernel_launch(void* const* d_in, const int* in_sizes, int n_in,
                              void* d_out, int out_size, void* d_ws, size_t ws_size,
                              hipStream_t stream)
{
    const float* feats     = (const float*)d_in[0];
    const float* wq_w      = (const float*)d_in[1];
    const float* wq_b      = (const float*)d_in[2];
    const float* wk_w      = (const float*)d_in[3];
    const float* wk_b      = (const float*)d_in[4];
    const int*   neighbors = (const int*)d_in[5];
    const int*   deg       = (const int*)d_in[6];
    float*       out       = (float*)d_out;

    // ws: [ej_new: NN i (doubles as ready flag)][pad][counter][pad][ei: NN f][ej_orig: NN f]
    char*  ws      = (char*)d_ws;
    int*   ej_new  = (int*)ws;
    int*   counter = ej_new + NN + 64;              // own cacheline
    float* ei      = (float*)(ws + (size_t)(NN + 128) * sizeof(int));
    float* ej_orig = ei + NN;

    (void)hipMemsetAsync(d_ws, 0, (size_t)(NN + 128) * sizeof(int), stream);

    dim3 pb(256), pg((NN + 3) / 4);
    precomp_kernel<<<pg, pb, 0, stream>>>(feats, wq_w, wq_b, wk_w, wk_b, ei, ej_orig);

    attn_dataflow<<<dim3(1024), dim3(256), 0, stream>>>(
        feats, neighbors, deg, ei, ej_orig, wk_w, wk_b, ej_new, counter, out);
}

// Round 5
// 427.881 us; speedup vs baseline: 16.6055x; 16.6055x over previous
//
#include <hip/hip_runtime.h>

// Graph-attention sequential sweep as dataflow over the dependency DAG.
// Node i depends only on out-rows g[j] for j in neighbors[i], j<i, k<deg[i].
//
// R5: single-variable experiment vs R3 — replace the global atomic counter
// with STATIC round-robin id assignment (wave g owns ids g, g+4096, ...).
// Same id->wave interleaving as counter@GRAB=1 (consecutive ids on distinct
// waves — R4 proved consecutive-ids-on-one-wave is catastrophic), but ZERO
// same-address atomics. Discriminates counter-serialization theory from
// handshake-chain theory.
//
// Deadlock-freedom: requires all 4096 waves co-resident. 1024 blocks x 256
// thr = 4 blocks/CU on 256 CUs; __launch_bounds__(256,4) caps VGPR at 128
// (R3 body compiles to ~48) -> 16 waves/CU residency (R2/R3 measured 45%
// occupancy at exactly this config). Smallest unfinished id u is owned by
// wave u%4096; its earlier ids are < u (finished), so it sits at u polling
// only finished deps -> progress.
//
// Body: R3's eager online-softmax, unchanged.
//  (a) neighbors accumulated the moment they are ready (non-deps first,
//      deps in publish order) with running-max rescaling.
//  (b) ej_new doubles as the ready flag (bits==0 => not ready; +0.0 results
//      nudged to a denormal).
//
// Coherence scheme (NO buffer_inv / NO buffer_wbl2 anywhere):
//  - producer: out-row stores write-through to LLC (sc0 sc1); ej_new via
//    relaxed agent atomic store, ordered after row stores by s_waitcnt(0).
//  - consumer: polls ej_new with relaxed agent loads (sc1, no L2 inv);
//    reads out-rows with NORMAL cached loads — safe because each 2KB row
//    occupies exclusive cachelines, is written once, and is first read only
//    after its ej_new is seen nonzero.

constexpr int NN = 50000;
constexpr int D  = 512;
constexpr int K  = 32;
constexpr int D4 = D / 4; // 128 float4 per row

typedef float v4f __attribute__((ext_vector_type(4)));

__device__ __forceinline__ void store_f4_llc(float* p, float4 v) {
    // write-through to the memory-side Infinity Cache (device coherence point)
    v4f vv; vv.x = v.x; vv.y = v.y; vv.z = v.z; vv.w = v.w;
    asm volatile("global_store_dwordx4 %0, %1, off sc0 sc1"
                 :: "v"(p), "v"(vv) : "memory");
}

__global__ __launch_bounds__(256) void precomp_kernel(
    const float* __restrict__ feats,
    const float* __restrict__ wq_w, const float* __restrict__ wq_b,
    const float* __restrict__ wk_w, const float* __restrict__ wk_b,
    float* __restrict__ ei, float* __restrict__ ej_orig)
{
    int gw   = (int)((blockIdx.x * blockDim.x + threadIdx.x) >> 6); // global wave id
    int lane = threadIdx.x & 63;
    if (gw >= NN) return;
    const float4* row = (const float4*)feats + (size_t)gw * D4;
    const float4* q4  = (const float4*)wq_w;
    const float4* k4  = (const float4*)wk_w;
    float dq = 0.f, dk = 0.f;
#pragma unroll
    for (int c = 0; c < 2; ++c) {
        float4 v  = row[lane + 64 * c];
        float4 q  = q4[lane + 64 * c];
        float4 kk = k4[lane + 64 * c];
        dq += v.x * q.x + v.y * q.y + v.z * q.z + v.w * q.w;
        dk += v.x * kk.x + v.y * kk.y + v.z * kk.z + v.w * kk.w;
    }
#pragma unroll
    for (int off = 32; off > 0; off >>= 1) {
        dq += __shfl_down(dq, off, 64);
        dk += __shfl_down(dk, off, 64);
    }
    if (lane == 0) {
        ei[gw]      = dq + wq_b[0];
        ej_orig[gw] = dk + wk_b[0];
    }
}

__global__ __launch_bounds__(256, 4) void attn_dataflow(
    const float* __restrict__ feats,
    const int* __restrict__ neighbors, const int* __restrict__ deg,
    const float* __restrict__ ei_arr, const float* __restrict__ ej_orig,
    const float* __restrict__ wk_w, const float* __restrict__ wk_b,
    int* ej_new,
    float* out)
{
    const int lane   = threadIdx.x & 63;
    const int gwave  = (int)((blockIdx.x * blockDim.x + threadIdx.x) >> 6);
    const int nwaves = (int)((gridDim.x * blockDim.x) >> 6);
    const float4* f4  = (const float4*)feats;
    const float4* o4r = (const float4*)out;
    const float4* wk4 = (const float4*)wk_w;
    const float   wkb = wk_b[0];

    for (int id = gwave; id < NN; id += nwaves) {
        const int d = deg[id];
        int nbr = 0;
        if (lane < K) nbr = neighbors[(size_t)id * K + lane];
        const bool valid = lane < d;                 // d <= 32
        const bool isdep = valid && (nbr < id);

        const float4 c0 = f4[(size_t)id * D4 + lane];
        const float4 c1 = f4[(size_t)id * D4 + lane + 64];
        const float eii = ei_arr[id];

        // eij known immediately for non-dep neighbors
        float eij = 0.f;
        if (valid && !isdep) eij = eii * ej_orig[nbr];

        // ---- eager online-softmax accumulation over ready neighbors ----
        float4 acc0 = {0.f, 0.f, 0.f, 0.f};
        float4 acc1 = {0.f, 0.f, 0.f, 0.f};
        float m = -3.0e38f, s = 0.f;

        unsigned long long pend = __ballot(valid && !isdep); // ready, unprocessed
        unsigned long long wait = __ballot(isdep);           // deps not yet ready

        while (pend | wait) {
            if (!pend) {
                // poll ALL remaining deps in parallel (one lane each)
                int pv = 0;
                const bool w = (wait >> lane) & 1ULL;
                if (w) pv = __hip_atomic_load(&ej_new[nbr], __ATOMIC_RELAXED,
                                              __HIP_MEMORY_SCOPE_AGENT);
                unsigned long long ready = __ballot(w && pv != 0);
                if (!ready) { __builtin_amdgcn_s_sleep(1); continue; }
                if (w && pv != 0) eij = eii * __int_as_float(pv);
                pend = ready;
                wait &= ~ready;
            }
            // take up to 4 ready neighbors (wave-uniform extraction)
            int cnt = 0;
            int   js[4]; float ee[4];
#pragma unroll
            for (int t = 0; t < 4; ++t) {
                if (pend) {
                    int k = (int)__ffsll(pend) - 1;
                    pend &= pend - 1;
                    ee[cnt] = __shfl(eij, k, 64);
                    js[cnt] = __shfl(nbr, k, 64);
                    ++cnt;
                }
            }
            // issue row loads FIRST so exp/rescale overlaps their flight
            float4 v0[4], v1[4];
#pragma unroll
            for (int t = 0; t < 4; ++t) {
                if (t < cnt) {
                    const float4* sp = (js[t] < id) ? (o4r + (size_t)js[t] * D4)
                                                    : (f4  + (size_t)js[t] * D4);
                    v0[t] = sp[lane];
                    v1[t] = sp[lane + 64];
                }
            }
            float mb = m;
#pragma unroll
            for (int t = 0; t < 4; ++t) if (t < cnt) mb = fmaxf(mb, ee[t]);
            if (mb > m) {
                const float r = __expf(m - mb);   // first time: exp(-inf)=0
                acc0.x *= r; acc0.y *= r; acc0.z *= r; acc0.w *= r;
                acc1.x *= r; acc1.y *= r; acc1.z *= r; acc1.w *= r;
                s *= r; m = mb;
            }
#pragma unroll
            for (int t = 0; t < 4; ++t) {
                if (t < cnt) {
                    const float wt = __expf(ee[t] - m);
                    s += wt;
                    acc0.x += wt * v0[t].x; acc0.y += wt * v0[t].y;
                    acc0.z += wt * v0[t].z; acc0.w += wt * v0[t].w;
                    acc1.x += wt * v1[t].x; acc1.y += wt * v1[t].y;
                    acc1.z += wt * v1[t].z; acc1.w += wt * v1[t].w;
                }
            }
        }

        const float inv_s = (s > 0.f) ? (1.0f / s) : 0.f;  // d==0 -> acc==0
        float4 g0 = {c0.x + acc0.x * inv_s, c0.y + acc0.y * inv_s,
                     c0.z + acc0.z * inv_s, c0.w + acc0.w * inv_s};
        float4 g1 = {c1.x + acc1.x * inv_s, c1.y + acc1.y * inv_s,
                     c1.z + acc1.z * inv_s, c1.w + acc1.w * inv_s};
        float* orow = out + (size_t)id * D;
        store_f4_llc(orow + 4 * lane,        g0);
        store_f4_llc(orow + 4 * (lane + 64), g1);

        // ej_new[id] = g . wk + bk  (computed while row stores are in flight)
        float4 w0 = wk4[lane], w1 = wk4[lane + 64];
        float pd = g0.x * w0.x + g0.y * w0.y + g0.z * w0.z + g0.w * w0.w
                 + g1.x * w1.x + g1.y * w1.y + g1.z * w1.z + g1.w * w1.w;
#pragma unroll
        for (int off = 32; off > 0; off >>= 1)
            pd += __shfl_xor(pd, off, 64);

        int bits = __float_as_int(pd + wkb);
        if (bits == 0) bits = 1;   // avoid the not-ready sentinel (+0.0 -> 1e-45)

        // order the row payload (at LLC) before the combined flag+payload
        __builtin_amdgcn_s_waitcnt(0);
        if (lane == 0)
            __hip_atomic_store(&ej_new[id], bits,
                               __ATOMIC_RELAXED, __HIP_MEMORY_SCOPE_AGENT);
    }
}

extern "C" void kernel_launch(void* const* d_in, const int* in_sizes, int n_in,
                              void* d_out, int out_size, void* d_ws, size_t ws_size,
                              hipStream_t stream)
{
    const float* feats     = (const float*)d_in[0];
    const float* wq_w      = (const float*)d_in[1];
    const float* wq_b      = (const float*)d_in[2];
    const float* wk_w      = (const float*)d_in[3];
    const float* wk_b      = (const float*)d_in[4];
    const int*   neighbors = (const int*)d_in[5];
    const int*   deg       = (const int*)d_in[6];
    float*       out       = (float*)d_out;

    // ws: [ej_new: NN i (doubles as ready flag)][pad][ei: NN f][ej_orig: NN f]
    char*  ws      = (char*)d_ws;
    int*   ej_new  = (int*)ws;
    float* ei      = (float*)(ws + (size_t)(NN + 128) * sizeof(int));
    float* ej_orig = ei + NN;

    (void)hipMemsetAsync(d_ws, 0, (size_t)(NN + 128) * sizeof(int), stream);

    dim3 pb(256), pg((NN + 3) / 4);
    precomp_kernel<<<pg, pb, 0, stream>>>(feats, wq_w, wq_b, wk_w, wk_b, ei, ej_orig);

    // 1024 blocks = 4096 waves, all co-resident (4 blocks/CU, launch_bounds(256,4))
    attn_dataflow<<<dim3(1024), dim3(256), 0, stream>>>(
        feats, neighbors, deg, ei, ej_orig, wk_w, wk_b, ej_new, out);
}